// Round 9
// baseline (380.230 us; speedup 1.0000x reference)
//
#include <hip/hip_runtime.h>
#include <math.h>

static constexpr int NN = 50000;   // nodes
static constexpr int NF = 128;     // features
static constexpr int NH = 64;      // hidden
static constexpr int NE = 1600000; // edges
static constexpr int NBUSED = (NN + 255) / 256;  // 196 buckets (col>>8)
static constexpr int NWG = 256;                  // partition workgroups
static constexpr int CHUNK = NE / NWG;           // 6250 edges per wg
static constexpr int NPW = 6;                    // nodes per wave (chunked aggs)
static constexpr int NWAVES = (NN + NPW - 1) / NPW;   // 8334
static constexpr int GWC = (NWAVES * 64 + 255) / 256; // 2084 blocks

typedef unsigned long long u64;
typedef float f32x2 __attribute__((ext_vector_type(2)));

// ---------------- helpers ----------------

__device__ __forceinline__ float bf2f(unsigned u) { return __uint_as_float(u << 16); }
__device__ __forceinline__ unsigned short f2bf(float f) {
  unsigned b = __float_as_uint(f);
  b += 0x7fffu + ((b >> 16) & 1u);  // RNE
  return (unsigned short)(b >> 16);
}
__device__ __forceinline__ float sigm(float x) { return 1.f / (1.f + __expf(-x)); }
__device__ __forceinline__ unsigned char f2fp8(float f) {
  int v = __builtin_amdgcn_cvt_pk_fp8_f32(f, f, 0, false);
  return (unsigned char)(v & 0xff);
}
// decode 16 fp8 (uint4) -> 16 f32
__device__ __forceinline__ void fp8x16_dec(uint4 v, float* o) {
  f32x2 t;
  t = __builtin_amdgcn_cvt_pk_f32_fp8(v.x, false); o[0] = t.x;  o[1] = t.y;
  t = __builtin_amdgcn_cvt_pk_f32_fp8(v.x, true);  o[2] = t.x;  o[3] = t.y;
  t = __builtin_amdgcn_cvt_pk_f32_fp8(v.y, false); o[4] = t.x;  o[5] = t.y;
  t = __builtin_amdgcn_cvt_pk_f32_fp8(v.y, true);  o[6] = t.x;  o[7] = t.y;
  t = __builtin_amdgcn_cvt_pk_f32_fp8(v.z, false); o[8] = t.x;  o[9] = t.y;
  t = __builtin_amdgcn_cvt_pk_f32_fp8(v.z, true);  o[10] = t.x; o[11] = t.y;
  t = __builtin_amdgcn_cvt_pk_f32_fp8(v.w, false); o[12] = t.x; o[13] = t.y;
  t = __builtin_amdgcn_cvt_pk_f32_fp8(v.w, true);  o[14] = t.x; o[15] = t.y;
}
// encode 16 f32 -> 16 fp8 (uint4)
__device__ __forceinline__ uint4 fp8x16_enc(const float* o) {
  uint4 r;
  int v;
  v = __builtin_amdgcn_cvt_pk_fp8_f32(o[0], o[1], 0, false);
  v = __builtin_amdgcn_cvt_pk_fp8_f32(o[2], o[3], v, true);
  r.x = (unsigned)v;
  v = __builtin_amdgcn_cvt_pk_fp8_f32(o[4], o[5], 0, false);
  v = __builtin_amdgcn_cvt_pk_fp8_f32(o[6], o[7], v, true);
  r.y = (unsigned)v;
  v = __builtin_amdgcn_cvt_pk_fp8_f32(o[8], o[9], 0, false);
  v = __builtin_amdgcn_cvt_pk_fp8_f32(o[10], o[11], v, true);
  r.z = (unsigned)v;
  v = __builtin_amdgcn_cvt_pk_fp8_f32(o[12], o[13], 0, false);
  v = __builtin_amdgcn_cvt_pk_fp8_f32(o[14], o[15], v, true);
  r.w = (unsigned)v;
  return r;
}

// ================= bucket-sort CSR build (no global per-edge atomics) =================

__global__ __launch_bounds__(256) void bhist_k(const int* __restrict__ col,
                                               int* __restrict__ counts) {
  __shared__ int cnt[256];
  cnt[threadIdx.x] = 0;
  __syncthreads();
  int g = blockIdx.x;
  int e1 = g * CHUNK + CHUNK;
  for (int e = g * CHUNK + threadIdx.x; e < e1; e += 256)
    atomicAdd(&cnt[col[e] >> 8], 1);
  __syncthreads();
  counts[g * 256 + threadIdx.x] = cnt[threadIdx.x];
}

__global__ __launch_bounds__(256) void bscan_k(int* __restrict__ counts) {
  __shared__ int sm[256];
  int b = threadIdx.x;
  int tot = 0;
  for (int g = 0; g < NWG; g++) tot += counts[g * 256 + b];
  sm[b] = tot;
  __syncthreads();
  int v = tot;
  for (int off = 1; off < 256; off <<= 1) {
    int u = (b >= off) ? sm[b - off] : 0;
    __syncthreads();
    sm[b] += u;
    __syncthreads();
  }
  int run = sm[b] - v;  // bucketStart[b]
  for (int g = 0; g < NWG; g++) {
    int c = counts[g * 256 + b];
    counts[g * 256 + b] = run;
    run += c;
  }
}

// partition edges to bucket-major; payload u64 = w<<32 | col_low<<16 | row
__global__ __launch_bounds__(256) void bpart_k(const int* __restrict__ row,
                                               const int* __restrict__ col,
                                               const float* __restrict__ w,
                                               const int* __restrict__ counts,
                                               u64* __restrict__ ebuf) {
  __shared__ int cur[256];
  int g = blockIdx.x;
  cur[threadIdx.x] = counts[g * 256 + threadIdx.x];
  __syncthreads();
  int e1 = g * CHUNK + CHUNK;
  for (int e = g * CHUNK + threadIdx.x; e < e1; e += 256) {
    int c = col[e];
    int p = atomicAdd(&cur[c >> 8], 1);
    u64 pk = ((u64)(unsigned)__float_as_int(w[e]) << 32) |
             ((unsigned)(c & 255) << 16) | (unsigned)row[e];
    ebuf[p] = pk;
  }
}

// per-bucket: per-col count + weighted degree (LDS), scan -> rowstart, dinv
__global__ __launch_bounds__(256) void bsortA_k(const u64* __restrict__ ebuf,
                                                const int* __restrict__ counts,
                                                int* __restrict__ rowstart,
                                                float* __restrict__ dinv) {
  __shared__ int cnt[256];
  __shared__ float deg[256];
  __shared__ int sm[256];
  int b = blockIdx.x, t = threadIdx.x;
  cnt[t] = 0;
  deg[t] = 1.0f;  // self-loop
  __syncthreads();
  int boff = counts[b];
  int bend = (b < NBUSED - 1) ? counts[b + 1] : NE;
  for (int e = boff + t; e < bend; e += 256) {
    u64 pk = ebuf[e];
    unsigned lo = (unsigned)pk;
    int c = (lo >> 16) & 255;
    atomicAdd(&cnt[c], 1);
    atomicAdd(&deg[c], __uint_as_float((unsigned)(pk >> 32)));
  }
  __syncthreads();
  int v = cnt[t];
  sm[t] = v;
  __syncthreads();
  for (int off = 1; off < 256; off <<= 1) {
    int u = (t >= off) ? sm[t - off] : 0;
    __syncthreads();
    sm[t] += u;
    __syncthreads();
  }
  int colg = b * 256 + t;
  if (colg < NN) {
    rowstart[colg] = boff + sm[t] - v;
    dinv[colg] = rsqrtf(deg[t]);
  }
  if (b == NBUSED - 1 && t == 0) rowstart[NN] = NE;
}

// per-bucket: place edges at LDS cursors -> es4 = (bf16(dinv[row]*w) << 16) | row
__global__ __launch_bounds__(256) void bsortB_k(const u64* __restrict__ ebuf,
                                                const int* __restrict__ counts,
                                                const int* __restrict__ rowstart,
                                                const float* __restrict__ dinv,
                                                unsigned* __restrict__ es4) {
  __shared__ int cur[256];
  int b = blockIdx.x, t = threadIdx.x;
  int colg = b * 256 + t;
  cur[t] = (colg < NN) ? rowstart[colg] : NE;
  __syncthreads();
  int boff = counts[b];
  int bend = (b < NBUSED - 1) ? counts[b + 1] : NE;
  for (int e = boff + t; e < bend; e += 256) {
    u64 pk = ebuf[e];
    unsigned lo = (unsigned)pk;
    int r = lo & 0xffff;
    int c = (lo >> 16) & 255;
    float wv = __uint_as_float((unsigned)(pk >> 32));
    int p = atomicAdd(&cur[c], 1);
    es4[p] = ((unsigned)f2bf(dinv[r] * wv) << 16) | (unsigned)r;
  }
}

// ---------------- small f32 GEMM: Y[N,M] = (X(+Xadd)) [N,K] @ W[K,M] ----------------
// XH: X is bf16. ACT: 0 none, 2 bias+sigmoid. OUTF/OUTH/OUT8: f32/bf16/fp8 outputs.
template<int K, int M, int ACT, bool OUTF, bool OUTH, bool XH, bool OUT8>
__global__ __launch_bounds__(256) void gemm_k(const float* __restrict__ X,
                                              const unsigned short* __restrict__ Xh,
                                              const float* __restrict__ Xadd,
                                              const float* __restrict__ W,
                                              const float* __restrict__ bias,
                                              float* __restrict__ Yf,
                                              unsigned short* __restrict__ Yh,
                                              unsigned char* __restrict__ Y8) {
  __shared__ float Ws[K * M];
  __shared__ float Xs[16][K];
  for (int i = threadIdx.x; i < K * M; i += 256) Ws[i] = W[i];
  int r0 = blockIdx.x * 16;
  for (int i = threadIdx.x; i < 16 * K; i += 256) {
    int r = i / K, k = i % K;
    size_t off = (size_t)(r0 + r) * K + k;
    float v = XH ? bf2f(Xh[off]) : X[off];
    if (Xadd) v += Xadd[off];
    Xs[r][k] = v;
  }
  __syncthreads();
  constexpr int RPT = 16 * M / 256;
  constexpr int RS = 256 / M;
  int colc = threadIdx.x % M;
  int rb = threadIdx.x / M;
  float acc[RPT];
#pragma unroll
  for (int i = 0; i < RPT; i++) acc[i] = 0.f;
  for (int k = 0; k < K; k++) {
    float wv = Ws[k * M + colc];
#pragma unroll
    for (int i = 0; i < RPT; i++) acc[i] += Xs[rb + i * RS][k] * wv;
  }
#pragma unroll
  for (int i = 0; i < RPT; i++) {
    int r = r0 + rb + i * RS;
    float o = acc[i];
    if (ACT > 0) o += bias[colc];
    if (ACT == 2) o = sigm(o);
    if (OUTF) Yf[(size_t)r * M + colc] = o;
    if (OUTH) Yh[(size_t)r * M + colc] = f2bf(o);
    if (OUT8) Y8[(size_t)r * M + colc] = f2fp8(o);
  }
}

// ------------- 64-ch chunked CSR gather-aggregate, fp8 src, fused epilogues ----------
// NPW contiguous nodes per wave; 16 edges/iter x 4 lanes x 16ch (16B loads).
// core: o[ch] = dinv_i*(sum_e nrm[e]*src[row[e]][ch] + dinv_i*src[i][ch])
// MODE 0: nrm=bf16(es4.hi);           relu(o+bias) -> fp8 out (conv1 -> h)
// MODE 1: nrm=bf16(es4.hi);           o            -> f32 out (conv2 pre-agg)
// MODE 2: nrm=dinv2[row]*bf16(es4.hi=ep); relu(o+bias) dot wfc -> block partial
template<int MODE>
__global__ __launch_bounds__(256, 8) void agg64_k(const int* __restrict__ rowstart,
                                                  const unsigned* __restrict__ es4,
                                                  const unsigned char* __restrict__ src8,
                                                  const float* __restrict__ dinv,
                                                  const float* __restrict__ bias,
                                                  unsigned char* __restrict__ out8,
                                                  float* __restrict__ outf,
                                                  const float* __restrict__ wfc) {
  int w = (blockIdx.x * 256 + threadIdx.x) >> 6;
  int n0 = w * NPW;
  int lane = threadIdx.x & 63;
  int sub = lane >> 2;  // edge slot 0..15
  int l = lane & 3;     // channels l*16 .. l*16+15
  float s = 0.f;        // MODE 2 running partial across nodes
  if (n0 < NN) {
    int n1 = min(n0 + NPW, NN);
    int e0 = rowstart[n0];
    for (int wid = n0; wid < n1; ++wid) {
      int e1 = rowstart[wid + 1];
      float di = dinv[wid];
      float a[16];
#pragma unroll
      for (int c = 0; c < 16; c++) a[c] = 0.f;
      for (int eb = e0; eb < e1; eb += 16) {
        int e = eb + sub;
        bool valid = e < e1;
        unsigned er = es4[valid ? e : eb];
        int r = (int)(er & 0xffffu);
        float nm;
        if (MODE == 2) nm = valid ? dinv[r] * bf2f(er >> 16) : 0.f;  // dinv2[r]*ep
        else nm = valid ? bf2f(er >> 16) : 0.f;
        uint4 v = *(const uint4*)(src8 + (size_t)r * 64 + l * 16);
        float t[16];
        fp8x16_dec(v, t);
#pragma unroll
        for (int c = 0; c < 16; c++) a[c] = fmaf(nm, t[c], a[c]);
      }
#pragma unroll
      for (int c = 0; c < 16; c++) {
        a[c] += __shfl_xor(a[c], 4);
        a[c] += __shfl_xor(a[c], 8);
        a[c] += __shfl_xor(a[c], 16);
        a[c] += __shfl_xor(a[c], 32);
      }
      uint4 sv = *(const uint4*)(src8 + (size_t)wid * 64 + l * 16);
      float sf[16];
      fp8x16_dec(sv, sf);
      if (MODE == 0) {
        if (sub == 0) {
          float o[16];
#pragma unroll
          for (int c4 = 0; c4 < 4; c4++) {
            float4 b4 = *(const float4*)(bias + l * 16 + c4 * 4);
            o[c4 * 4 + 0] = fmaxf(di * (a[c4 * 4 + 0] + di * sf[c4 * 4 + 0]) + b4.x, 0.f);
            o[c4 * 4 + 1] = fmaxf(di * (a[c4 * 4 + 1] + di * sf[c4 * 4 + 1]) + b4.y, 0.f);
            o[c4 * 4 + 2] = fmaxf(di * (a[c4 * 4 + 2] + di * sf[c4 * 4 + 2]) + b4.z, 0.f);
            o[c4 * 4 + 3] = fmaxf(di * (a[c4 * 4 + 3] + di * sf[c4 * 4 + 3]) + b4.w, 0.f);
          }
          *(uint4*)(out8 + (size_t)wid * 64 + l * 16) = fp8x16_enc(o);
        }
      } else if (MODE == 1) {
        if (sub == 0) {
#pragma unroll
          for (int c4 = 0; c4 < 4; c4++) {
            float4 o4;
            o4.x = di * (a[c4 * 4 + 0] + di * sf[c4 * 4 + 0]);
            o4.y = di * (a[c4 * 4 + 1] + di * sf[c4 * 4 + 1]);
            o4.z = di * (a[c4 * 4 + 2] + di * sf[c4 * 4 + 2]);
            o4.w = di * (a[c4 * 4 + 3] + di * sf[c4 * 4 + 3]);
            *(float4*)(outf + (size_t)wid * 64 + l * 16 + c4 * 4) = o4;
          }
        }
      } else {
        if (sub == 0) {
#pragma unroll
          for (int c4 = 0; c4 < 4; c4++) {
            float4 b4 = *(const float4*)(bias + l * 16 + c4 * 4);
            float4 w4 = *(const float4*)(wfc + (size_t)wid * 64 + l * 16 + c4 * 4);
            float o0 = fmaxf(di * (a[c4 * 4 + 0] + di * sf[c4 * 4 + 0]) + b4.x, 0.f);
            float o1 = fmaxf(di * (a[c4 * 4 + 1] + di * sf[c4 * 4 + 1]) + b4.y, 0.f);
            float o2 = fmaxf(di * (a[c4 * 4 + 2] + di * sf[c4 * 4 + 2]) + b4.z, 0.f);
            float o3 = fmaxf(di * (a[c4 * 4 + 3] + di * sf[c4 * 4 + 3]) + b4.w, 0.f);
            s += o0 * w4.x + o1 * w4.y + o2 * w4.z + o3 * w4.w;
          }
        }
      }
      e0 = e1;
    }
  }
  if (MODE == 2) {
    s += __shfl_xor(s, 1);
    s += __shfl_xor(s, 2);
    __shared__ float bs[4];
    if (lane == 0) bs[threadIdx.x >> 6] = s;
    __syncthreads();
    if (threadIdx.x == 0) outf[blockIdx.x] = bs[0] + bs[1] + bs[2] + bs[3];
  }
}

// ------- edge probs + disc degree, chunked: fp8 z, 8 lanes/edge, 8 edges/iter -------
// writes ep (bf16) into es4 hi-half in place; dinv2[i] = rsqrt(1 + sum ep)
__global__ __launch_bounds__(256, 8) void eprob8_k(const int* __restrict__ rowstart,
                                                   unsigned* __restrict__ es4,
                                                   const unsigned char* __restrict__ z8,
                                                   float* __restrict__ dinv2) {
  int w = (blockIdx.x * 256 + threadIdx.x) >> 6;
  int n0 = w * NPW;
  if (n0 >= NN) return;
  int n1 = min(n0 + NPW, NN);
  int lane = threadIdx.x & 63;
  int sub = lane >> 3;  // edge slot 0..7
  int l = lane & 7;     // 16 channels at l*16
  int e0 = rowstart[n0];
  for (int wid = n0; wid < n1; ++wid) {
    int e1 = rowstart[wid + 1];
    uint4 zv = *(const uint4*)(z8 + (size_t)wid * NF + l * 16);
    float zi[16];
    fp8x16_dec(zv, zi);
    float sum = 0.f;
    for (int eb = e0; eb < e1; eb += 8) {
      int e = eb + sub;
      bool valid = e < e1;
      unsigned er = es4[valid ? e : eb];
      int r = (int)(er & 0xffffu);
      uint4 v = *(const uint4*)(z8 + (size_t)r * NF + l * 16);
      float zr[16];
      fp8x16_dec(v, zr);
      float d = 0.f;
#pragma unroll
      for (int c = 0; c < 16; c++) d = fmaf(zr[c], zi[c], d);
      d += __shfl_xor(d, 1);
      d += __shfl_xor(d, 2);
      d += __shfl_xor(d, 4);
      if (valid && l == 0) {
        float p = sigm(d);
        es4[e] = ((unsigned)f2bf(p) << 16) | (unsigned)r;
        sum += p;
      }
    }
    sum += __shfl_xor(sum, 8);
    sum += __shfl_xor(sum, 16);
    sum += __shfl_xor(sum, 32);
    if (lane == 0) dinv2[wid] = rsqrtf(1.f + sum);
    e0 = e1;
  }
}

// ---------------- final reduce: sigmoid(sum(partials) + bfc) ----------------
__global__ __launch_bounds__(256) void reduce_k(const float* __restrict__ partials, int n,
                                                const float* __restrict__ bfc,
                                                float* __restrict__ out) {
  float s = 0.f;
  for (int i = threadIdx.x; i < n; i += 256) s += partials[i];
  s += __shfl_xor(s, 1);
  s += __shfl_xor(s, 2);
  s += __shfl_xor(s, 4);
  s += __shfl_xor(s, 8);
  s += __shfl_xor(s, 16);
  s += __shfl_xor(s, 32);
  __shared__ float ws4[4];
  if ((threadIdx.x & 63) == 0) ws4[threadIdx.x >> 6] = s;
  __syncthreads();
  if (threadIdx.x == 0) out[0] = sigm(ws4[0] + ws4[1] + ws4[2] + ws4[3] + bfc[0]);
}

// ---------------- launch ----------------

extern "C" void kernel_launch(void* const* d_in, const int* in_sizes, int n_in,
                              void* d_out, int out_size, void* d_ws, size_t ws_size,
                              hipStream_t stream) {
  const float* features = (const float*)d_in[0];
  const int* edge_index = (const int*)d_in[1];  // [2, E] int32
  const float* edge_attr = (const float*)d_in[2];
  const float* Wg1 = (const float*)d_in[3];
  const float* bg1 = (const float*)d_in[4];
  const float* Wg2 = (const float*)d_in[5];
  const float* bg2 = (const float*)d_in[6];
  const float* Wd1 = (const float*)d_in[7];
  const float* bd1 = (const float*)d_in[8];
  const float* wfc = (const float*)d_in[9];
  const float* bfc = (const float*)d_in[10];
  float* out = (float*)d_out;

  const int* row = edge_index;
  const int* col = edge_index + NE;

  // workspace carve (byte-based, 256B aligned)
  char* wsb = (char*)d_ws;
  auto carve = [&](size_t bytes) {
    void* p = wsb;
    wsb += (bytes + 255) & ~(size_t)255;
    return p;
  };
  int*   counts   = (int*)carve((size_t)NWG * 256 * 4);  // [g][b]
  int*   rowstart = (int*)carve((NN + 1) * 4);
  float* dinv     = (float*)carve(NN * 4);
  float* dinv2    = (float*)carve(NN * 4);
  u64*   ebuf     = (u64*)carve((size_t)NE * 8);    // bucket-partitioned packed edges
  unsigned* es4   = (unsigned*)carve((size_t)NE * 4);  // (bf16 nrm/ep)<<16 | row
  unsigned char* xw8a = (unsigned char*)carve((size_t)NN * NH);       // conv1 xw fp8
  unsigned char* hh8  = (unsigned char*)carve((size_t)NN * NH);       // h fp8
  float* ah   = (float*)carve((size_t)NN * NH * 4);                   // prop(h) f32
  unsigned short* zh = (unsigned short*)carve((size_t)NN * NF * 2);   // z bf16 (gemm3 in)
  unsigned char* z8  = (unsigned char*)carve((size_t)NN * NF);        // z fp8 (eprob)
  unsigned char* xw8d = (unsigned char*)carve((size_t)NN * NH);       // disc xw fp8
  float* partials = (float*)carve((size_t)GWC * 4);

  const int GG = NN / 16;  // 3125

  // --- bucket-sort CSR build ---
  bhist_k<<<NWG, 256, 0, stream>>>(col, counts);
  bscan_k<<<1, 256, 0, stream>>>(counts);
  bpart_k<<<NWG, 256, 0, stream>>>(row, col, edge_attr, counts, ebuf);
  bsortA_k<<<NBUSED, 256, 0, stream>>>(ebuf, counts, rowstart, dinv);
  bsortB_k<<<NBUSED, 256, 0, stream>>>(ebuf, counts, rowstart, dinv, es4);

  // --- conv1: h = relu(prop(features @ Wg1) + bg1), xw + h in fp8 ---
  gemm_k<NF, NH, 0, false, false, false, true><<<GG, 256, 0, stream>>>(
      features, nullptr, nullptr, Wg1, nullptr, nullptr, nullptr, xw8a);
  agg64_k<0><<<GWC, 256, 0, stream>>>(rowstart, es4, xw8a, dinv, bg1, hh8, nullptr, nullptr);

  // --- conv2 (commuted): z = sigmoid(prop(h) @ Wg2 + bg2), z in bf16 + fp8 ---
  agg64_k<1><<<GWC, 256, 0, stream>>>(rowstart, es4, hh8, dinv, nullptr, nullptr, ah, nullptr);
  gemm_k<NH, NF, 2, false, true, false, true><<<GG, 256, 0, stream>>>(
      ah, nullptr, nullptr, Wg2, bg2, nullptr, zh, z8);

  // --- edge probs + disc degree (fused); bf16 ep written into es4 hi ---
  eprob8_k<<<GWC, 256, 0, stream>>>(rowstart, es4, z8, dinv2);

  // --- disc conv fused with final dot: partials[b] = sum relu(...)*wfc ---
  gemm_k<NF, NH, 0, false, false, true, true><<<GG, 256, 0, stream>>>(
      nullptr, zh, features, Wd1, nullptr, nullptr, nullptr, xw8d);
  agg64_k<2><<<GWC, 256, 0, stream>>>(rowstart, es4, xw8d, dinv2, bd1, nullptr, partials, wfc);

  // --- final: sigmoid(sum(partials) + bfc) ---
  reduce_k<<<1, 256, 0, stream>>>(partials, GWC, bfc, out);
}

// Round 10
// 335.646 us; speedup vs baseline: 1.1328x; 1.1328x over previous
//
#include <hip/hip_runtime.h>
#include <math.h>

static constexpr int NN = 50000;   // nodes
static constexpr int NF = 128;     // features
static constexpr int NH = 64;      // hidden
static constexpr int NE = 1600000; // edges
static constexpr int NBUSED = (NN + 255) / 256;  // 196 buckets (col>>8)
static constexpr int NWG = 256;                  // partition workgroups
static constexpr int CHUNK = NE / NWG;           // 6250 edges per wg

typedef unsigned long long u64;
typedef float f32x2 __attribute__((ext_vector_type(2)));

// ---------------- helpers ----------------

__device__ __forceinline__ float bf2f(unsigned u) { return __uint_as_float(u << 16); }
__device__ __forceinline__ unsigned short f2bf(float f) {
  unsigned b = __float_as_uint(f);
  b += 0x7fffu + ((b >> 16) & 1u);  // RNE
  return (unsigned short)(b >> 16);
}
__device__ __forceinline__ float sigm(float x) { return 1.f / (1.f + __expf(-x)); }
__device__ __forceinline__ unsigned char f2fp8(float f) {
  int v = __builtin_amdgcn_cvt_pk_fp8_f32(f, f, 0, false);
  return (unsigned char)(v & 0xff);
}
// decode 16 fp8 (uint4) -> 16 f32
__device__ __forceinline__ void fp8x16_dec(uint4 v, float* o) {
  f32x2 t;
  t = __builtin_amdgcn_cvt_pk_f32_fp8(v.x, false); o[0] = t.x;  o[1] = t.y;
  t = __builtin_amdgcn_cvt_pk_f32_fp8(v.x, true);  o[2] = t.x;  o[3] = t.y;
  t = __builtin_amdgcn_cvt_pk_f32_fp8(v.y, false); o[4] = t.x;  o[5] = t.y;
  t = __builtin_amdgcn_cvt_pk_f32_fp8(v.y, true);  o[6] = t.x;  o[7] = t.y;
  t = __builtin_amdgcn_cvt_pk_f32_fp8(v.z, false); o[8] = t.x;  o[9] = t.y;
  t = __builtin_amdgcn_cvt_pk_f32_fp8(v.z, true);  o[10] = t.x; o[11] = t.y;
  t = __builtin_amdgcn_cvt_pk_f32_fp8(v.w, false); o[12] = t.x; o[13] = t.y;
  t = __builtin_amdgcn_cvt_pk_f32_fp8(v.w, true);  o[14] = t.x; o[15] = t.y;
}
// encode 16 f32 -> 16 fp8 (uint4)
__device__ __forceinline__ uint4 fp8x16_enc(const float* o) {
  uint4 r;
  int v;
  v = __builtin_amdgcn_cvt_pk_fp8_f32(o[0], o[1], 0, false);
  v = __builtin_amdgcn_cvt_pk_fp8_f32(o[2], o[3], v, true);
  r.x = (unsigned)v;
  v = __builtin_amdgcn_cvt_pk_fp8_f32(o[4], o[5], 0, false);
  v = __builtin_amdgcn_cvt_pk_fp8_f32(o[6], o[7], v, true);
  r.y = (unsigned)v;
  v = __builtin_amdgcn_cvt_pk_fp8_f32(o[8], o[9], 0, false);
  v = __builtin_amdgcn_cvt_pk_fp8_f32(o[10], o[11], v, true);
  r.z = (unsigned)v;
  v = __builtin_amdgcn_cvt_pk_fp8_f32(o[12], o[13], 0, false);
  v = __builtin_amdgcn_cvt_pk_fp8_f32(o[14], o[15], v, true);
  r.w = (unsigned)v;
  return r;
}

// ================= bucket-sort CSR build (no global per-edge atomics) =================

__global__ __launch_bounds__(256) void bhist_k(const int* __restrict__ col,
                                               int* __restrict__ counts) {
  __shared__ int cnt[256];
  cnt[threadIdx.x] = 0;
  __syncthreads();
  int g = blockIdx.x;
  int e1 = g * CHUNK + CHUNK;
  for (int e = g * CHUNK + threadIdx.x; e < e1; e += 256)
    atomicAdd(&cnt[col[e] >> 8], 1);
  __syncthreads();
  counts[g * 256 + threadIdx.x] = cnt[threadIdx.x];
}

__global__ __launch_bounds__(256) void bscan_k(int* __restrict__ counts) {
  __shared__ int sm[256];
  int b = threadIdx.x;
  int tot = 0;
  for (int g = 0; g < NWG; g++) tot += counts[g * 256 + b];
  sm[b] = tot;
  __syncthreads();
  int v = tot;
  for (int off = 1; off < 256; off <<= 1) {
    int u = (b >= off) ? sm[b - off] : 0;
    __syncthreads();
    sm[b] += u;
    __syncthreads();
  }
  int run = sm[b] - v;  // bucketStart[b]
  for (int g = 0; g < NWG; g++) {
    int c = counts[g * 256 + b];
    counts[g * 256 + b] = run;
    run += c;
  }
}

// partition edges to bucket-major; payload u64 = w<<32 | col_low<<16 | row
__global__ __launch_bounds__(256) void bpart_k(const int* __restrict__ row,
                                               const int* __restrict__ col,
                                               const float* __restrict__ w,
                                               const int* __restrict__ counts,
                                               u64* __restrict__ ebuf) {
  __shared__ int cur[256];
  int g = blockIdx.x;
  cur[threadIdx.x] = counts[g * 256 + threadIdx.x];
  __syncthreads();
  int e1 = g * CHUNK + CHUNK;
  for (int e = g * CHUNK + threadIdx.x; e < e1; e += 256) {
    int c = col[e];
    int p = atomicAdd(&cur[c >> 8], 1);
    u64 pk = ((u64)(unsigned)__float_as_int(w[e]) << 32) |
             ((unsigned)(c & 255) << 16) | (unsigned)row[e];
    ebuf[p] = pk;
  }
}

// per-bucket: per-col count + weighted degree (LDS), scan -> rowstart, dinv
__global__ __launch_bounds__(256) void bsortA_k(const u64* __restrict__ ebuf,
                                                const int* __restrict__ counts,
                                                int* __restrict__ rowstart,
                                                float* __restrict__ dinv) {
  __shared__ int cnt[256];
  __shared__ float deg[256];
  __shared__ int sm[256];
  int b = blockIdx.x, t = threadIdx.x;
  cnt[t] = 0;
  deg[t] = 1.0f;  // self-loop
  __syncthreads();
  int boff = counts[b];
  int bend = (b < NBUSED - 1) ? counts[b + 1] : NE;
  for (int e = boff + t; e < bend; e += 256) {
    u64 pk = ebuf[e];
    unsigned lo = (unsigned)pk;
    int c = (lo >> 16) & 255;
    atomicAdd(&cnt[c], 1);
    atomicAdd(&deg[c], __uint_as_float((unsigned)(pk >> 32)));
  }
  __syncthreads();
  int v = cnt[t];
  sm[t] = v;
  __syncthreads();
  for (int off = 1; off < 256; off <<= 1) {
    int u = (t >= off) ? sm[t - off] : 0;
    __syncthreads();
    sm[t] += u;
    __syncthreads();
  }
  int colg = b * 256 + t;
  if (colg < NN) {
    rowstart[colg] = boff + sm[t] - v;
    dinv[colg] = rsqrtf(deg[t]);
  }
  if (b == NBUSED - 1 && t == 0) rowstart[NN] = NE;
}

// per-bucket: place edges at LDS cursors -> es4 = (bf16(dinv[row]*w) << 16) | row
__global__ __launch_bounds__(256) void bsortB_k(const u64* __restrict__ ebuf,
                                                const int* __restrict__ counts,
                                                const int* __restrict__ rowstart,
                                                const float* __restrict__ dinv,
                                                unsigned* __restrict__ es4) {
  __shared__ int cur[256];
  int b = blockIdx.x, t = threadIdx.x;
  int colg = b * 256 + t;
  cur[t] = (colg < NN) ? rowstart[colg] : NE;
  __syncthreads();
  int boff = counts[b];
  int bend = (b < NBUSED - 1) ? counts[b + 1] : NE;
  for (int e = boff + t; e < bend; e += 256) {
    u64 pk = ebuf[e];
    unsigned lo = (unsigned)pk;
    int r = lo & 0xffff;
    int c = (lo >> 16) & 255;
    float wv = __uint_as_float((unsigned)(pk >> 32));
    int p = atomicAdd(&cur[c], 1);
    es4[p] = ((unsigned)f2bf(dinv[r] * wv) << 16) | (unsigned)r;
  }
}

// ---------------- small f32 GEMM: Y[N,M] = (X(+Xadd)) [N,K] @ W[K,M] ----------------
// XH: X is bf16. ACT: 0 none, 2 bias+sigmoid. OUTF/OUTH/OUT8: f32/bf16/fp8 outputs.
template<int K, int M, int ACT, bool OUTF, bool OUTH, bool XH, bool OUT8>
__global__ __launch_bounds__(256) void gemm_k(const float* __restrict__ X,
                                              const unsigned short* __restrict__ Xh,
                                              const float* __restrict__ Xadd,
                                              const float* __restrict__ W,
                                              const float* __restrict__ bias,
                                              float* __restrict__ Yf,
                                              unsigned short* __restrict__ Yh,
                                              unsigned char* __restrict__ Y8) {
  __shared__ float Ws[K * M];
  __shared__ float Xs[16][K];
  for (int i = threadIdx.x; i < K * M; i += 256) Ws[i] = W[i];
  int r0 = blockIdx.x * 16;
  for (int i = threadIdx.x; i < 16 * K; i += 256) {
    int r = i / K, k = i % K;
    size_t off = (size_t)(r0 + r) * K + k;
    float v = XH ? bf2f(Xh[off]) : X[off];
    if (Xadd) v += Xadd[off];
    Xs[r][k] = v;
  }
  __syncthreads();
  constexpr int RPT = 16 * M / 256;
  constexpr int RS = 256 / M;
  int colc = threadIdx.x % M;
  int rb = threadIdx.x / M;
  float acc[RPT];
#pragma unroll
  for (int i = 0; i < RPT; i++) acc[i] = 0.f;
  for (int k = 0; k < K; k++) {
    float wv = Ws[k * M + colc];
#pragma unroll
    for (int i = 0; i < RPT; i++) acc[i] += Xs[rb + i * RS][k] * wv;
  }
#pragma unroll
  for (int i = 0; i < RPT; i++) {
    int r = r0 + rb + i * RS;
    float o = acc[i];
    if (ACT > 0) o += bias[colc];
    if (ACT == 2) o = sigm(o);
    if (OUTF) Yf[(size_t)r * M + colc] = o;
    if (OUTH) Yh[(size_t)r * M + colc] = f2bf(o);
    if (OUT8) Y8[(size_t)r * M + colc] = f2fp8(o);
  }
}

// ------------- 64-ch CSR gather-aggregate, fp8 src, 32 edges/iter -------------
// one wave per node; 2 edge slots per lane group (sub, sub+16) -> 2 gathers in flight.
// core: o[ch] = dinv_i*(sum_e nrm[e]*src[row[e]][ch] + dinv_i*src[i][ch])
// MODE 0: nrm=bf16(es4.hi);               relu(o+bias) -> fp8 out  (conv1 -> h)
// MODE 1: nrm=bf16(es4.hi);               o            -> bf16 out (conv2 pre-agg)
// MODE 2: nrm=dinv2[row]*bf16(es4.hi=ep); relu(o+bias) dot wfc -> block partial
template<int MODE>
__global__ __launch_bounds__(256) void agg64_k(const int* __restrict__ rowstart,
                                               const unsigned* __restrict__ es4,
                                               const unsigned char* __restrict__ src8,
                                               const float* __restrict__ dinv,
                                               const float* __restrict__ bias,
                                               unsigned char* __restrict__ out8,
                                               unsigned short* __restrict__ outh,
                                               float* __restrict__ outf,
                                               const float* __restrict__ wfc) {
  int wid = (blockIdx.x * 256 + threadIdx.x) >> 6;  // exact grid: wid < NN
  int lane = threadIdx.x & 63;
  int sub = lane >> 2;  // edge slot 0..15 (and +16)
  int l = lane & 3;     // channels l*16 .. l*16+15
  int e0 = rowstart[wid], e1 = rowstart[wid + 1];
  float di = dinv[wid];
  float a[16];
#pragma unroll
  for (int c = 0; c < 16; c++) a[c] = 0.f;
  for (int eb = e0; eb < e1; eb += 32) {
    int eA = eb + sub;
    int eB = eb + 16 + sub;
    bool vA = eA < e1, vB = eB < e1;
    unsigned erA = es4[vA ? eA : e0];
    unsigned erB = es4[vB ? eB : e0];
    int rA = (int)(erA & 0xffffu);
    int rB = (int)(erB & 0xffffu);
    float nmA, nmB;
    if (MODE == 2) {
      nmA = vA ? dinv[rA] * bf2f(erA >> 16) : 0.f;  // dinv2[r]*ep
      nmB = vB ? dinv[rB] * bf2f(erB >> 16) : 0.f;
    } else {
      nmA = vA ? bf2f(erA >> 16) : 0.f;
      nmB = vB ? bf2f(erB >> 16) : 0.f;
    }
    uint4 gA = *(const uint4*)(src8 + (size_t)rA * 64 + l * 16);
    uint4 gB = *(const uint4*)(src8 + (size_t)rB * 64 + l * 16);
    float tA[16], tB[16];
    fp8x16_dec(gA, tA);
    fp8x16_dec(gB, tB);
#pragma unroll
    for (int c = 0; c < 16; c++) a[c] = fmaf(nmA, tA[c], a[c]);
#pragma unroll
    for (int c = 0; c < 16; c++) a[c] = fmaf(nmB, tB[c], a[c]);
  }
#pragma unroll
  for (int c = 0; c < 16; c++) {
    a[c] += __shfl_xor(a[c], 4);
    a[c] += __shfl_xor(a[c], 8);
    a[c] += __shfl_xor(a[c], 16);
    a[c] += __shfl_xor(a[c], 32);
  }
  uint4 sv = *(const uint4*)(src8 + (size_t)wid * 64 + l * 16);
  float sf[16];
  fp8x16_dec(sv, sf);

  if (MODE == 0) {
    if (sub == 0) {
      float o[16];
#pragma unroll
      for (int c4 = 0; c4 < 4; c4++) {
        float4 b4 = *(const float4*)(bias + l * 16 + c4 * 4);
        o[c4 * 4 + 0] = fmaxf(di * (a[c4 * 4 + 0] + di * sf[c4 * 4 + 0]) + b4.x, 0.f);
        o[c4 * 4 + 1] = fmaxf(di * (a[c4 * 4 + 1] + di * sf[c4 * 4 + 1]) + b4.y, 0.f);
        o[c4 * 4 + 2] = fmaxf(di * (a[c4 * 4 + 2] + di * sf[c4 * 4 + 2]) + b4.z, 0.f);
        o[c4 * 4 + 3] = fmaxf(di * (a[c4 * 4 + 3] + di * sf[c4 * 4 + 3]) + b4.w, 0.f);
      }
      *(uint4*)(out8 + (size_t)wid * 64 + l * 16) = fp8x16_enc(o);
    }
  } else if (MODE == 1) {
    if (sub == 0) {
      float o[16];
#pragma unroll
      for (int c = 0; c < 16; c++) o[c] = di * (a[c] + di * sf[c]);
      uint4 p0, p1;
      p0.x = (unsigned)f2bf(o[0]) | ((unsigned)f2bf(o[1]) << 16);
      p0.y = (unsigned)f2bf(o[2]) | ((unsigned)f2bf(o[3]) << 16);
      p0.z = (unsigned)f2bf(o[4]) | ((unsigned)f2bf(o[5]) << 16);
      p0.w = (unsigned)f2bf(o[6]) | ((unsigned)f2bf(o[7]) << 16);
      p1.x = (unsigned)f2bf(o[8]) | ((unsigned)f2bf(o[9]) << 16);
      p1.y = (unsigned)f2bf(o[10]) | ((unsigned)f2bf(o[11]) << 16);
      p1.z = (unsigned)f2bf(o[12]) | ((unsigned)f2bf(o[13]) << 16);
      p1.w = (unsigned)f2bf(o[14]) | ((unsigned)f2bf(o[15]) << 16);
      *(uint4*)(outh + (size_t)wid * 64 + l * 16) = p0;
      *(uint4*)(outh + (size_t)wid * 64 + l * 16 + 8) = p1;
    }
  } else {
    float s = 0.f;
    if (sub == 0) {
#pragma unroll
      for (int c4 = 0; c4 < 4; c4++) {
        float4 b4 = *(const float4*)(bias + l * 16 + c4 * 4);
        float4 w4 = *(const float4*)(wfc + (size_t)wid * 64 + l * 16 + c4 * 4);
        float o0 = fmaxf(di * (a[c4 * 4 + 0] + di * sf[c4 * 4 + 0]) + b4.x, 0.f);
        float o1 = fmaxf(di * (a[c4 * 4 + 1] + di * sf[c4 * 4 + 1]) + b4.y, 0.f);
        float o2 = fmaxf(di * (a[c4 * 4 + 2] + di * sf[c4 * 4 + 2]) + b4.z, 0.f);
        float o3 = fmaxf(di * (a[c4 * 4 + 3] + di * sf[c4 * 4 + 3]) + b4.w, 0.f);
        s += o0 * w4.x + o1 * w4.y + o2 * w4.z + o3 * w4.w;
      }
    }
    s += __shfl_xor(s, 1);
    s += __shfl_xor(s, 2);
    __shared__ float bs[4];
    if (lane == 0) bs[threadIdx.x >> 6] = s;
    __syncthreads();
    if (threadIdx.x == 0) outf[blockIdx.x] = bs[0] + bs[1] + bs[2] + bs[3];
  }
}

// ------- edge probs + disc degree: fp8 z, 16 edges/iter (2 gathers in flight) -------
// writes ep (bf16) into es4 hi-half in place; dinv2[i] = rsqrt(1 + sum ep)
__global__ __launch_bounds__(256) void eprob16_k(const int* __restrict__ rowstart,
                                                 unsigned* __restrict__ es4,
                                                 const unsigned char* __restrict__ z8,
                                                 float* __restrict__ dinv2) {
  int wid = (blockIdx.x * 256 + threadIdx.x) >> 6;  // exact grid: wid < NN
  int lane = threadIdx.x & 63;
  int sub = lane >> 3;  // edge slot 0..7 (and +8)
  int l = lane & 7;     // 16 channels at l*16
  uint4 zv = *(const uint4*)(z8 + (size_t)wid * NF + l * 16);
  float zi[16];
  fp8x16_dec(zv, zi);
  int e0 = rowstart[wid], e1 = rowstart[wid + 1];
  float sum = 0.f;
  for (int eb = e0; eb < e1; eb += 16) {
    int eA = eb + sub;
    int eB = eb + 8 + sub;
    bool vA = eA < e1, vB = eB < e1;
    unsigned erA = es4[vA ? eA : e0];
    unsigned erB = es4[vB ? eB : e0];
    int rA = (int)(erA & 0xffffu);
    int rB = (int)(erB & 0xffffu);
    uint4 a4 = *(const uint4*)(z8 + (size_t)rA * NF + l * 16);
    uint4 b4 = *(const uint4*)(z8 + (size_t)rB * NF + l * 16);
    float zr[16];
    fp8x16_dec(a4, zr);
    float dA = 0.f;
#pragma unroll
    for (int c = 0; c < 16; c++) dA = fmaf(zr[c], zi[c], dA);
    fp8x16_dec(b4, zr);
    float dB = 0.f;
#pragma unroll
    for (int c = 0; c < 16; c++) dB = fmaf(zr[c], zi[c], dB);
    dA += __shfl_xor(dA, 1);
    dA += __shfl_xor(dA, 2);
    dA += __shfl_xor(dA, 4);
    dB += __shfl_xor(dB, 1);
    dB += __shfl_xor(dB, 2);
    dB += __shfl_xor(dB, 4);
    if (vA && l == 0) {
      float p = sigm(dA);
      es4[eA] = ((unsigned)f2bf(p) << 16) | (unsigned)rA;
      sum += p;
    }
    if (vB && l == 0) {
      float p = sigm(dB);
      es4[eB] = ((unsigned)f2bf(p) << 16) | (unsigned)rB;
      sum += p;
    }
  }
  sum += __shfl_xor(sum, 8);
  sum += __shfl_xor(sum, 16);
  sum += __shfl_xor(sum, 32);
  if (lane == 0) dinv2[wid] = rsqrtf(1.f + sum);
}

// ---------------- final reduce: sigmoid(sum(partials) + bfc) ----------------
__global__ __launch_bounds__(256) void reduce_k(const float* __restrict__ partials, int n,
                                                const float* __restrict__ bfc,
                                                float* __restrict__ out) {
  float s = 0.f;
  for (int i = threadIdx.x; i < n; i += 256) s += partials[i];
  s += __shfl_xor(s, 1);
  s += __shfl_xor(s, 2);
  s += __shfl_xor(s, 4);
  s += __shfl_xor(s, 8);
  s += __shfl_xor(s, 16);
  s += __shfl_xor(s, 32);
  __shared__ float ws4[4];
  if ((threadIdx.x & 63) == 0) ws4[threadIdx.x >> 6] = s;
  __syncthreads();
  if (threadIdx.x == 0) out[0] = sigm(ws4[0] + ws4[1] + ws4[2] + ws4[3] + bfc[0]);
}

// ---------------- launch ----------------

extern "C" void kernel_launch(void* const* d_in, const int* in_sizes, int n_in,
                              void* d_out, int out_size, void* d_ws, size_t ws_size,
                              hipStream_t stream) {
  const float* features = (const float*)d_in[0];
  const int* edge_index = (const int*)d_in[1];  // [2, E] int32
  const float* edge_attr = (const float*)d_in[2];
  const float* Wg1 = (const float*)d_in[3];
  const float* bg1 = (const float*)d_in[4];
  const float* Wg2 = (const float*)d_in[5];
  const float* bg2 = (const float*)d_in[6];
  const float* Wd1 = (const float*)d_in[7];
  const float* bd1 = (const float*)d_in[8];
  const float* wfc = (const float*)d_in[9];
  const float* bfc = (const float*)d_in[10];
  float* out = (float*)d_out;

  const int* row = edge_index;
  const int* col = edge_index + NE;

  // workspace carve (byte-based, 256B aligned)
  char* wsb = (char*)d_ws;
  auto carve = [&](size_t bytes) {
    void* p = wsb;
    wsb += (bytes + 255) & ~(size_t)255;
    return p;
  };
  int*   counts   = (int*)carve((size_t)NWG * 256 * 4);  // [g][b]
  int*   rowstart = (int*)carve((NN + 1) * 4);
  float* dinv     = (float*)carve(NN * 4);
  float* dinv2    = (float*)carve(NN * 4);
  u64*   ebuf     = (u64*)carve((size_t)NE * 8);       // bucket-partitioned packed edges
  unsigned* es4   = (unsigned*)carve((size_t)NE * 4);  // (bf16 nrm/ep)<<16 | row
  unsigned char* xw8a = (unsigned char*)carve((size_t)NN * NH);       // conv1 xw fp8
  unsigned char* hh8  = (unsigned char*)carve((size_t)NN * NH);       // h fp8
  unsigned short* ahh = (unsigned short*)carve((size_t)NN * NH * 2);  // prop(h) bf16
  unsigned short* zh = (unsigned short*)carve((size_t)NN * NF * 2);   // z bf16 (gemm3 in)
  unsigned char* z8  = (unsigned char*)carve((size_t)NN * NF);        // z fp8 (eprob)
  unsigned char* xw8d = (unsigned char*)carve((size_t)NN * NH);       // disc xw fp8
  float* partials = (float*)carve(12500 * 4);

  const int GG = NN / 16;        // 3125
  const int GW = NN * 64 / 256;  // 12500 (exact, one wave per node)

  // --- bucket-sort CSR build ---
  bhist_k<<<NWG, 256, 0, stream>>>(col, counts);
  bscan_k<<<1, 256, 0, stream>>>(counts);
  bpart_k<<<NWG, 256, 0, stream>>>(row, col, edge_attr, counts, ebuf);
  bsortA_k<<<NBUSED, 256, 0, stream>>>(ebuf, counts, rowstart, dinv);
  bsortB_k<<<NBUSED, 256, 0, stream>>>(ebuf, counts, rowstart, dinv, es4);

  // --- conv1: h = relu(prop(features @ Wg1) + bg1), xw + h in fp8 ---
  gemm_k<NF, NH, 0, false, false, false, true><<<GG, 256, 0, stream>>>(
      features, nullptr, nullptr, Wg1, nullptr, nullptr, nullptr, xw8a);
  agg64_k<0><<<GW, 256, 0, stream>>>(rowstart, es4, xw8a, dinv, bg1, hh8, nullptr, nullptr,
                                     nullptr);

  // --- conv2 (commuted): z = sigmoid(prop(h) @ Wg2 + bg2), pre-agg bf16, z bf16+fp8 ---
  agg64_k<1><<<GW, 256, 0, stream>>>(rowstart, es4, hh8, dinv, nullptr, nullptr, ahh, nullptr,
                                     nullptr);
  gemm_k<NH, NF, 2, false, true, true, true><<<GG, 256, 0, stream>>>(
      nullptr, ahh, nullptr, Wg2, bg2, nullptr, zh, z8);

  // --- edge probs + disc degree (fused); bf16 ep written into es4 hi ---
  eprob16_k<<<GW, 256, 0, stream>>>(rowstart, es4, z8, dinv2);

  // --- disc conv fused with final dot: partials[b] = sum relu(...)*wfc ---
  gemm_k<NF, NH, 0, false, false, true, true><<<GG, 256, 0, stream>>>(
      nullptr, zh, features, Wd1, nullptr, nullptr, nullptr, xw8d);
  agg64_k<2><<<GW, 256, 0, stream>>>(rowstart, es4, xw8d, dinv2, bd1, nullptr, nullptr,
                                     partials, wfc);

  // --- final: sigmoid(sum(partials) + bfc) ---
  reduce_k<<<1, 256, 0, stream>>>(partials, GW, bfc, out);
}